// Round 10
// baseline (219.936 us; speedup 1.0000x reference)
//
#include <hip/hip_runtime.h>

#define TLEN 1024
#define CDIM 256
#define NHEAD 4
#define HD 64
#define WIN_ 128
#define PADL 63
#define LWIN 1023
#define TPAD 1150
#define SW 32        // windows per strip: 32 strips x 4 heads x 2 variants = 256 blocks

typedef __attribute__((ext_vector_type(8))) short bf16x8;
typedef __attribute__((ext_vector_type(4))) float f32x4;

__device__ __forceinline__ int prow(int v, int t) {
  if (v == 0) return t;
  if (t < PADL || t >= PADL + TLEN) return t;
  int s = t - PADL;
  s = (s + (TLEN - 64)) & (TLEN - 1);   // roll(x, +64)
  return PADL + s;
}

__device__ __forceinline__ float hannf(int j) {
  return 0.5f * (1.0f - __cosf(6.283185307179586f * (float)j / 127.0f));
}

__device__ __forceinline__ float countf(int t) {
  int lo = t - 127; if (lo < 0) lo = 0;
  int hi = t;       if (hi > LWIN - 1) hi = LWIN - 1;
  return (float)(hi - lo + 1);
}

__device__ __forceinline__ unsigned short bfr(float f) {  // fp32 -> bf16 RTNE
  unsigned int u = __float_as_uint(f);
  u += 0x7FFFu + ((u >> 16) & 1u);
  return (unsigned short)(u >> 16);
}
// pack two f32 -> bf16x2 by truncation, single v_perm_b32
__device__ __forceinline__ unsigned int pk2t(float a, float b) {
  return __builtin_amdgcn_perm(__float_as_uint(b), __float_as_uint(a), 0x07060302u);
}
__device__ __forceinline__ float bfu(unsigned short u) {
  return __uint_as_float(((unsigned int)u) << 16);
}
__device__ __forceinline__ float bflo(unsigned int u) { return __uint_as_float(u << 16); }
__device__ __forceinline__ float bfhi(unsigned int u) { return __uint_as_float(u & 0xFFFF0000u); }

// ---------------- fused prep: LN->bf16 | castw | mmat | zero accg | zero Pbf pads+msum ----------------
__global__ void k_prep(const float* __restrict__ x, const float* __restrict__ g,
                       const float* __restrict__ b, unsigned short* __restrict__ lnbf,
                       const float* __restrict__ W, unsigned short* __restrict__ Wb,
                       const float* __restrict__ pw, const float* __restrict__ ow,
                       const float* __restrict__ ob, unsigned short* __restrict__ Mtb,
                       float* __restrict__ vbv,
                       float* __restrict__ accg, unsigned short* __restrict__ Pbf,
                       float* __restrict__ msum) {
  __shared__ float pr[256];
  __shared__ float red[256];
  const int bid = blockIdx.x;
  const int tid = threadIdx.x;
  if (bid < 256) {
    int wv = tid >> 6, lane = tid & 63;
    int r = bid * 4 + wv;
    float4 v = ((const float4*)(x + (size_t)r * CDIM))[lane];
    float s = v.x + v.y + v.z + v.w;
    float q = v.x * v.x + v.y * v.y + v.z * v.z + v.w * v.w;
    #pragma unroll
    for (int m = 32; m >= 1; m >>= 1) { s += __shfl_xor(s, m); q += __shfl_xor(q, m); }
    float mu = s * (1.0f / 256.0f);
    float var = q * (1.0f / 256.0f) - mu * mu;
    float rs = rsqrtf(var + 1e-5f);
    float4 gg = ((const float4*)g)[lane];
    float4 bb = ((const float4*)b)[lane];
    uint2 o;
    o.x = (unsigned int)bfr((v.x - mu) * rs * gg.x + bb.x) |
          ((unsigned int)bfr((v.y - mu) * rs * gg.y + bb.y) << 16);
    o.y = (unsigned int)bfr((v.z - mu) * rs * gg.z + bb.z) |
          ((unsigned int)bfr((v.w - mu) * rs * gg.w + bb.w) << 16);
    ((uint2*)(lnbf + (size_t)r * CDIM))[lane] = o;
  } else if (bid < 352) {
    int i = (bid - 256) * 256 + tid;
    const float4* src = (const float4*)W;
    float4 a = src[2 * i], c = src[2 * i + 1];
    uint4 o;
    o.x = (unsigned int)bfr(a.x) | ((unsigned int)bfr(a.y) << 16);
    o.y = (unsigned int)bfr(a.z) | ((unsigned int)bfr(a.w) << 16);
    o.z = (unsigned int)bfr(c.x) | ((unsigned int)bfr(c.y) << 16);
    o.w = (unsigned int)bfr(c.z) | ((unsigned int)bfr(c.w) << 16);
    ((uint4*)Wb)[i] = o;
  } else if (bid < 608) {
    const int e = bid - 352;
    pr[tid] = pw[(size_t)e * CDIM + tid];
    __syncthreads();
    float a0 = 0.f, a1 = 0.f, a2 = 0.f, a3 = 0.f;
    for (int m = 0; m < 256; m += 4) {
      a0 += pr[m] * ow[(size_t)m * CDIM + tid];
      a1 += pr[m + 1] * ow[(size_t)(m + 1) * CDIM + tid];
      a2 += pr[m + 2] * ow[(size_t)(m + 2) * CDIM + tid];
      a3 += pr[m + 3] * ow[(size_t)(m + 3) * CDIM + tid];
    }
    Mtb[(size_t)e * CDIM + tid] = bfr((a0 + a1) + (a2 + a3));
    red[tid] = pr[tid] * ob[tid];
    __syncthreads();
    for (int s = 128; s > 0; s >>= 1) { if (tid < s) red[tid] += red[tid + s]; __syncthreads(); }
    if (tid == 0) vbv[e] = red[0];
  } else if (bid < 624) {
    uint4 zz = make_uint4(0, 0, 0, 0);
    for (int i = (bid - 608) * 256 + tid; i < 147200; i += 16 * 256)
      ((uint4*)accg)[i] = zz;
  } else {
    uint4 zz = make_uint4(0, 0, 0, 0);
    for (int i = (bid - 624) * 256 + tid; i < 12096; i += 16 * 256) {
      int idx = (i < 6048) ? i : (104352 + (i - 6048));
      ((uint4*)Pbf)[idx] = zz;
    }
    if (bid == 624 && tid < 64) ((float4*)msum)[tid] = make_float4(0.f, 0.f, 0.f, 0.f);
  }
}

// ---------------- P projection via MFMA ----------------
__launch_bounds__(512, 1)
__global__ void k_proj(const unsigned short* __restrict__ lnbf,
                       const unsigned short* __restrict__ Wb,
                       unsigned short* __restrict__ Pbf) {
  const int tid = threadIdx.x;
  const int lane = tid & 63, wv = tid >> 6;
  const int li16 = lane & 15, q4 = lane >> 4;
  const int ws = wv & 1, we = wv >> 1;
  const int s0 = blockIdx.x * 128 + ws * 64;
  const int e0 = blockIdx.y * 128 + we * 32;

  f32x4 acc[4][2];
  #pragma unroll
  for (int it = 0; it < 4; ++it)
    #pragma unroll
    for (int et = 0; et < 2; ++et) acc[it][et] = (f32x4){0.f, 0.f, 0.f, 0.f};

  #pragma unroll
  for (int ks = 0; ks < 8; ++ks) {
    bf16x8 Af[4], Bf[2];
    #pragma unroll
    for (int it = 0; it < 4; ++it)
      Af[it] = *(const bf16x8*)(lnbf + (size_t)(s0 + 16 * it + li16) * 256 + ks * 32 + q4 * 8);
    #pragma unroll
    for (int et = 0; et < 2; ++et)
      Bf[et] = *(const bf16x8*)(Wb + (size_t)(e0 + 16 * et + li16) * 256 + ks * 32 + q4 * 8);
    #pragma unroll
    for (int it = 0; it < 4; ++it)
      #pragma unroll
      for (int et = 0; et < 2; ++et)
        acc[it][et] = __builtin_amdgcn_mfma_f32_16x16x32_bf16(Af[it], Bf[et], acc[it][et], 0, 0, 0);
  }
  #pragma unroll
  for (int it = 0; it < 4; ++it)
    #pragma unroll
    for (int et = 0; et < 2; ++et)
      #pragma unroll
      for (int r = 0; r < 4; ++r) {
        int srow = s0 + 16 * it + 4 * q4 + r;
        int e = e0 + 16 * et + li16;
        Pbf[(size_t)(PADL + srow) * 768 + e] = bfr(acc[it][et][r]);
      }
}

// ---------------- V' staging (256 threads): V'[j][d]=E(j)*h_j*Pv; row 64=E(j) ----------------
__device__ __forceinline__ void stage_v(const unsigned short* __restrict__ Pbf,
                                        unsigned short* vt, int v, int hd,
                                        int l0, int w, int tid,
                                        const float* __restrict__ bB,
                                        const float* __restrict__ hth) {
  const int jp = tid & 63;
  const int j0 = 2 * jp;
  const int p0 = w + j0;
  int row0 = prow(v, l0 + w + j0);
  int row1 = prow(v, l0 + w + j0 + 1);
  const unsigned short* b0 = Pbf + (size_t)row0 * 768 + 512 + hd * 64;
  const unsigned short* b1 = Pbf + (size_t)row1 * 768 + 512 + hd * 64;
  float h0 = hth[j0], h1 = hth[j0 + 1];
  float e0 = __expf(h0 * bB[p0] * 0.125f);
  float e1 = __expf(h1 * bB[p0 + 1] * 0.125f);
  float f0 = e0 * h0, f1 = e1 * h1;
  #pragma unroll
  for (int pass = 0; pass < 2; ++pass) {
    int dg = (tid >> 6) + 4 * pass;          // 0..3 then 4..7
    uint4 a = *(const uint4*)(b0 + dg * 8);
    uint4 b = *(const uint4*)(b1 + dg * 8);
    unsigned int av[4] = {a.x, a.y, a.z, a.w};
    unsigned int bv[4] = {b.x, b.y, b.z, b.w};
    #pragma unroll
    for (int q = 0; q < 4; ++q) {
      int d0 = dg * 8 + 2 * q;
      unsigned int w0 = pk2t(f0 * bflo(av[q]), f1 * bflo(bv[q]));
      unsigned int w1 = pk2t(f0 * bfhi(av[q]), f1 * bfhi(bv[q]));
      *(unsigned int*)&vt[d0 * 128 + (j0 ^ ((d0 & 7) << 3))] = w0;
      *(unsigned int*)&vt[(d0 + 1) * 128 + (j0 ^ (((d0 + 1) & 7) << 3))] = w1;
    }
  }
  if (tid < 64) {   // E row at d=64 (swizzle 0)
    *(unsigned int*)&vt[64 * 128 + j0] = pk2t(e0, e1);
  }
}

// ---------------- MFMA attention: 4 waves, 2 i-tiles per wave (register blocking) ----------------
__launch_bounds__(256, 1)
__global__ void k_attn(const unsigned short* __restrict__ Pbf, const float* __restrict__ ipb,
                       float* __restrict__ accg) {
  __shared__ __align__(16) unsigned short Pq[159 * 64];    // swizzle blk d^((t&7)<<3)
  __shared__ __align__(16) unsigned short Pk[159 * 64];
  __shared__ __align__(16) unsigned short Vt[2][80 * 128]; // rows 0..63 V', 64 E, 65..79 zero
  __shared__ __align__(16) unsigned short Ab[128 * 128];   // A''=exp, swizzle j^((i&7)<<3)
  __shared__ __align__(16) float accs[159 * 68];
  __shared__ float hth[128];
  __shared__ float bB[160];
  __shared__ float bqS[64];

  const int strip = blockIdx.x, hd = blockIdx.y, v = blockIdx.z;
  const int l0 = strip * SW;
  const int nw = (SW < LWIN - l0) ? SW : (LWIN - l0);
  const int span = nw - 1 + WIN_;
  const int tid = threadIdx.x;
  const int lane = tid & 63, wv = tid >> 6;     // 4 waves
  const int li16 = lane & 15, q4 = lane >> 4;
  const int i0 = 32 * wv + li16;                // first owned row; second is i0+16

  for (int i = tid; i < 159 * 68; i += 256) accs[i] = 0.0f;
  if (tid < 128) hth[tid] = hannf(tid);
  if (tid < 64) bqS[tid] = ipb[hd * 64 + tid];
  for (int i = tid; i < span * 8; i += 256) {
    int t = i >> 3, dg = i & 7;
    int row = prow(v, l0 + t);
    const unsigned short* src = Pbf + (size_t)row * 768 + hd * 64;
    uint4 q = *(const uint4*)(src + dg * 8);
    uint4 k = *(const uint4*)(src + 256 + dg * 8);
    int off = (dg * 8) ^ ((t & 7) << 3);
    *(uint4*)&Pq[t * 64 + off] = q;
    *(uint4*)&Pk[t * 64 + off] = k;
  }
  // zero Vt pad rows 65..79 of both buffers (240 uint4 each)
  {
    uint4 zz = make_uint4(0, 0, 0, 0);
    for (int i = tid; i < 480; i += 256) {
      int bidx = i / 240, k = i % 240;
      *(uint4*)&Vt[bidx][65 * 128 + k * 8] = zz;
    }
  }
  __syncthreads();

  // bias-dot array b(t) = bq·Pk(t)
  for (int p = tid; p < span; p += 256) {
    float b = 0.0f;
    int sw = (p & 7) << 3;
    for (int d = 0; d < 64; ++d) b += bqS[d] * bfu(Pk[p * 64 + (d ^ sw)]);
    bB[p] = b;
  }
  __syncthreads();          // bB ready before stage_v reads it
  stage_v(Pbf, &Vt[0][0], v, hd, l0, 0, tid, bB, hth);
  __syncthreads();

  // per-thread hhj[m] = h_j(m)/8; h_i for the two owned rows
  float hhj[32];
  #pragma unroll
  for (int tj = 0; tj < 8; ++tj)
    #pragma unroll
    for (int r = 0; r < 4; ++r)
      hhj[tj * 4 + r] = hth[16 * tj + 4 * q4 + r] * 0.125f;
  const float hi0 = hth[i0];
  const float hi1 = hth[i0 + 16];

  #pragma unroll 1
  for (int w = 0; w < nw; ++w) {
    // ---- S^T[j][i] for both i-tiles; Kf shared ----
    bf16x8 Qf[2][2];
    #pragma unroll
    for (int it = 0; it < 2; ++it) {
      int t = w + i0 + 16 * it, sw = (t & 7) << 3;
      Qf[it][0] = *(bf16x8*)&Pq[t * 64 + ((8 * q4) ^ sw)];
      Qf[it][1] = *(bf16x8*)&Pq[t * 64 + ((32 + 8 * q4) ^ sw)];
    }
    f32x4 S[2][8];
    #pragma unroll
    for (int it = 0; it < 2; ++it)
      #pragma unroll
      for (int tj = 0; tj < 8; ++tj) S[it][tj] = (f32x4){0.f, 0.f, 0.f, 0.f};
    #pragma unroll
    for (int tj = 0; tj < 8; ++tj) {
      int t = w + 16 * tj + li16, sw = (t & 7) << 3;
      bf16x8 Kf0 = *(bf16x8*)&Pk[t * 64 + ((8 * q4) ^ sw)];
      bf16x8 Kf1 = *(bf16x8*)&Pk[t * 64 + ((32 + 8 * q4) ^ sw)];
      S[0][tj] = __builtin_amdgcn_mfma_f32_16x16x32_bf16(Kf0, Qf[0][0], S[0][tj], 0, 0, 0);
      S[0][tj] = __builtin_amdgcn_mfma_f32_16x16x32_bf16(Kf1, Qf[0][1], S[0][tj], 0, 0, 0);
      S[1][tj] = __builtin_amdgcn_mfma_f32_16x16x32_bf16(Kf0, Qf[1][0], S[1][tj], 0, 0, 0);
      S[1][tj] = __builtin_amdgcn_mfma_f32_16x16x32_bf16(Kf1, Qf[1][1], S[1][tj], 0, 0, 0);
    }

    // ---- A'' = exp(h_i*h_j/8 * S); pack into Ab (wave-private rows) ----
    #pragma unroll
    for (int it = 0; it < 2; ++it) {
      const float hi = it ? hi1 : hi0;
      const int irow = i0 + 16 * it;
      const int sw = (irow & 7) << 3;
      #pragma unroll
      for (int tj = 0; tj < 8; ++tj) {
        #pragma unroll
        for (int r = 0; r < 4; ++r)
          S[it][tj][r] = __expf(hi * hhj[tj * 4 + r] * S[it][tj][r]);
        uint2 o;
        o.x = pk2t(S[it][tj][0], S[it][tj][1]);
        o.y = pk2t(S[it][tj][2], S[it][tj][3]);
        *(uint2*)&Ab[irow * 128 + ((16 * tj + 4 * q4) ^ sw)] = o;
      }
    }

    // ---- O'^T[d][i] = sum_j V'[d][j]*A''[i][j]; Af shared across i-tiles; tile 4 = normalizer ----
    f32x4 O[2][5];
    #pragma unroll
    for (int it = 0; it < 2; ++it)
      #pragma unroll
      for (int mt = 0; mt < 5; ++mt) O[it][mt] = (f32x4){0.f, 0.f, 0.f, 0.f};
    const unsigned short* vt = &Vt[w & 1][0];
    {
      const int sw0 = (i0 & 7) << 3;
      #pragma unroll
      for (int ks = 0; ks < 4; ++ks) {
        bf16x8 Bf0 = *(bf16x8*)&Ab[i0 * 128 + ((32 * ks + 8 * q4) ^ sw0)];
        bf16x8 Bf1 = *(bf16x8*)&Ab[(i0 + 16) * 128 + ((32 * ks + 8 * q4) ^ sw0)];
        #pragma unroll
        for (int mt = 0; mt < 5; ++mt) {
          int d = 16 * mt + li16;
          bf16x8 Af = *(bf16x8*)&vt[d * 128 + ((32 * ks + 8 * q4) ^ ((d & 7) << 3))];
          O[0][mt] = __builtin_amdgcn_mfma_f32_16x16x32_bf16(Af, Bf0, O[0][mt], 0, 0, 0);
          O[1][mt] = __builtin_amdgcn_mfma_f32_16x16x32_bf16(Af, Bf1, O[1][mt], 0, 0, 0);
        }
      }
    }

    // ---- normalizers (E row lives at q4=0, reg 0 of tile 4) ----
    float sc0 = 1.0f / __shfl(O[0][4][0], li16);
    float sc1 = 1.0f / __shfl(O[1][4][0], li16);

    // ---- accumulate O^T * sc (vector RMW, bijective row ownership) ----
    #pragma unroll
    for (int it = 0; it < 2; ++it) {
      const float sc = it ? sc1 : sc0;
      float* arow = &accs[(w + i0 + 16 * it) * 68];
      #pragma unroll
      for (int mt = 0; mt < 4; ++mt) {
        int c = 16 * mt + 4 * q4;
        float4 cur = *(float4*)&arow[c];
        cur.x += O[it][mt][0] * sc; cur.y += O[it][mt][1] * sc;
        cur.z += O[it][mt][2] * sc; cur.w += O[it][mt][3] * sc;
        *(float4*)&arow[c] = cur;
      }
    }

    if (w + 1 < nw) stage_v(Pbf, &Vt[(w + 1) & 1][0], v, hd, l0, w + 1, tid, bB, hth);
    __syncthreads();
  }

  // ---- epilogue: + cnt*bv, atomic into global ----
  float* av = accg + (size_t)v * TPAD * CDIM;
  for (int i = tid; i < span * 64; i += 256) {
    int p = i >> 6, dd = i & 63;
    int lo = p - 127; if (lo < 0) lo = 0;
    int hi = p; if (hi > nw - 1) hi = nw - 1;
    float cnt = (float)(hi - lo + 1);
    float bvd = ipb[512 + hd * 64 + dd];
    atomicAdd(&av[(size_t)(l0 + p) * CDIM + hd * 64 + dd],
              accs[p * 68 + dd] + cnt * bvd);
  }
}

// ---------------- combine variants + merged projection (MFMA) ----------------
__launch_bounds__(512, 1)
__global__ void k_comb(const float* __restrict__ accg, const unsigned short* __restrict__ Mtb,
                       const float* __restrict__ vbv, const float* __restrict__ pb,
                       float* __restrict__ z, float* __restrict__ msum) {
  __shared__ __align__(16) unsigned short Ub[128 * 264];
  __shared__ float cfA[128], cfB[128], bscL[128];
  __shared__ float msB[256];
  const int tid = threadIdx.x;
  const int lane = tid & 63, wv = tid >> 6;
  const int li16 = lane & 15, q4 = lane >> 4;
  const int tw = wv & 1, ew = wv >> 1;
  const int t0 = blockIdx.x * 128;
  const int e0 = blockIdx.y * 128;

  if (tid < 128) {
    int s = t0 + tid;
    float c0 = countf(PADL + s);
    float c1 = countf(PADL + ((s + 64) & (TLEN - 1)));
    float fA = 0.5f / (c0 + 1e-6f), fB = 0.5f / (c1 + 1e-6f);
    cfA[tid] = fA; cfB[tid] = fB;
    bscL[tid] = c0 * fA + c1 * fB;
  }
  if (tid < 256) msB[tid] = 0.0f;
  __syncthreads();

  for (int i = tid; i < 128 * 128; i += 512) {
    int rr = i >> 7, c2 = (i & 127) * 2;
    int s = t0 + rr;
    int s1 = (s + 64) & (TLEN - 1);
    float2 a0 = *(const float2*)&accg[(size_t)(PADL + s) * CDIM + c2];
    float2 a1 = *(const float2*)&accg[(size_t)TPAD * CDIM + (size_t)(PADL + s1) * CDIM + c2];
    float fA = cfA[rr], fB = cfB[rr];
    *(unsigned int*)&Ub[rr * 264 + c2] =
        pk2t(a0.x * fA + a1.x * fB, a0.y * fA + a1.y * fB);
  }
  __syncthreads();

  f32x4 acc[4][2];
  #pragma unroll
  for (int it = 0; it < 4; ++it)
    #pragma unroll
    for (int et = 0; et < 2; ++et) acc[it][et] = (f32x4){0.f, 0.f, 0.f, 0.f};
  #pragma unroll
  for (int ks = 0; ks < 8; ++ks) {
    bf16x8 Af[4], Bf[2];
    #pragma unroll
    for (int it = 0; it < 4; ++it)
      Af[it] = *(bf16x8*)&Ub[(tw * 64 + 16 * it + li16) * 264 + ks * 32 + q4 * 8];
    #pragma unroll
    for (int et = 0; et < 2; ++et)
      Bf[et] = *(const bf16x8*)(Mtb + (size_t)(e0 + ew * 32 + 16 * et + li16) * 256 + ks * 32 + q4 * 8);
    #pragma unroll
    for (int it = 0; it < 4; ++it)
      #pragma unroll
      for (int et = 0; et < 2; ++et)
        acc[it][et] = __builtin_amdgcn_mfma_f32_16x16x32_bf16(Af[it], Bf[et], acc[it][et], 0, 0, 0);
  }

  #pragma unroll
  for (int et = 0; et < 2; ++et) {
    int e = e0 + ew * 32 + 16 * et + li16;
    float vbe = vbv[e], pbe = pb[e];
    float part = 0.0f;
    #pragma unroll
    for (int it = 0; it < 4; ++it)
      #pragma unroll
      for (int r = 0; r < 4; ++r) {
        int rloc = tw * 64 + 16 * it + 4 * q4 + r;
        float val = acc[it][et][r] + bscL[rloc] * vbe + pbe;
        z[(size_t)(t0 + rloc) * CDIM + e] = val;
        part += val;
      }
    atomicAdd(&msB[e - e0 + (e0 & 128)], part);
  }
  __syncthreads();
  if (tid < 128) atomicAdd(&msum[e0 + tid], msB[tid + (e0 & 128)]);
}

// ---------------- fused SE gate + residual ----------------
__global__ void k_finalse(const float* __restrict__ x, const float* __restrict__ z,
                          const float* __restrict__ msum, const float* __restrict__ w1,
                          const float* __restrict__ w2, float* __restrict__ out) {
  __shared__ float red2[16][4];
  __shared__ float s1[16];
  __shared__ float gateS[256];
  int tid = threadIdx.x;
  int lane = tid & 63, wv = tid >> 6;
  float sm = msum[tid] * (1.0f / 1024.0f);
  #pragma unroll
  for (int r = 0; r < 16; ++r) {
    float v = sm * w1[(size_t)r * 256 + tid];
    #pragma unroll
    for (int m = 32; m >= 1; m >>= 1) v += __shfl_xor(v, m);
    if (lane == 0) red2[r][wv] = v;
  }
  __syncthreads();
  if (tid < 16) {
    float a = red2[tid][0] + red2[tid][1] + red2[tid][2] + red2[tid][3];
    s1[tid] = fmaxf(a, 0.0f);
  }
  __syncthreads();
  float gacc = 0.0f;
  #pragma unroll
  for (int i = 0; i < 16; ++i) gacc += s1[i] * w2[(size_t)tid * 16 + i];
  gateS[tid] = 1.0f / (1.0f + __expf(-gacc));
  __syncthreads();
  int i = blockIdx.x * 256 + tid;
  float4 xv = ((const float4*)x)[i];
  float4 zv = ((const float4*)z)[i];
  float4 gv = ((const float4*)gateS)[i & 63];
  float4 o;
  o.x = xv.x + zv.x * gv.x;
  o.y = xv.y + zv.y * gv.y;
  o.z = xv.z + zv.z * gv.z;
  o.w = xv.w + zv.w * gv.w;
  ((float4*)out)[i] = o;
}

extern "C" void kernel_launch(void* const* d_in, const int* in_sizes, int n_in,
                              void* d_out, int out_size, void* d_ws, size_t ws_size,
                              hipStream_t stream) {
  const float* x   = (const float*)d_in[0];
  const float* lng = (const float*)d_in[1];
  const float* lnb = (const float*)d_in[2];
  const float* ipw = (const float*)d_in[3];
  const float* ipb = (const float*)d_in[4];
  const float* ow  = (const float*)d_in[5];
  const float* ob  = (const float*)d_in[6];
  const float* pw  = (const float*)d_in[7];
  const float* pb  = (const float*)d_in[8];
  const float* w1  = (const float*)d_in[9];
  const float* w2  = (const float*)d_in[10];
  float* out = (float*)d_out;

  float* ws = (float*)d_ws;
  unsigned short* lnbf = (unsigned short*)ws;             // 131072 f
  unsigned short* Wb   = (unsigned short*)(ws + 131072);  // 98304 f
  unsigned short* Pbf  = (unsigned short*)(ws + 229376);  // 441600 f
  float* accg = ws + 229376 + 441600;                     // 588800 f
  unsigned short* Mtb = (unsigned short*)(accg + 588800); // 32768 f
  float* vbv  = accg + 588800 + 32768;                    // 256
  float* z    = vbv + 256;                                // 262144
  float* msum = z + 262144;                               // 256

  k_prep<<<dim3(640), dim3(256), 0, stream>>>(x, lng, lnb, lnbf, ipw, Wb,
                                              pw, ow, ob, Mtb, vbv, accg, Pbf, msum);
  k_proj<<<dim3(8, 6), dim3(512), 0, stream>>>(lnbf, Wb, Pbf);
  k_attn<<<dim3(32, NHEAD, 2), dim3(256), 0, stream>>>(Pbf, ipb, accg);
  k_comb<<<dim3(8, 2), dim3(512), 0, stream>>>(accg, Mtb, vbv, pb, z, msum);
  k_finalse<<<dim3(256), dim3(256), 0, stream>>>(x, z, msum, w1, w2, out);
}

// Round 12
// 192.544 us; speedup vs baseline: 1.1423x; 1.1423x over previous
//
#include <hip/hip_runtime.h>

#define TLEN 1024
#define CDIM 256
#define NHEAD 4
#define HD 64
#define WIN_ 128
#define PADL 63
#define LWIN 1023
#define TPAD 1150
#define SW 32        // windows per strip: 32 strips x 4 heads x 2 variants = 256 blocks

typedef __attribute__((ext_vector_type(8))) short bf16x8;
typedef __attribute__((ext_vector_type(4))) float f32x4;

__device__ __forceinline__ int prow(int v, int t) {
  if (v == 0) return t;
  if (t < PADL || t >= PADL + TLEN) return t;
  int s = t - PADL;
  s = (s + (TLEN - 64)) & (TLEN - 1);   // roll(x, +64)
  return PADL + s;
}

__device__ __forceinline__ float hannf(int j) {
  return 0.5f * (1.0f - __cosf(6.283185307179586f * (float)j / 127.0f));
}

__device__ __forceinline__ float countf(int t) {
  int lo = t - 127; if (lo < 0) lo = 0;
  int hi = t;       if (hi > LWIN - 1) hi = LWIN - 1;
  return (float)(hi - lo + 1);
}

__device__ __forceinline__ unsigned short bfr(float f) {  // fp32 -> bf16 RTNE
  unsigned int u = __float_as_uint(f);
  u += 0x7FFFu + ((u >> 16) & 1u);
  return (unsigned short)(u >> 16);
}
// pack two f32 -> bf16x2 by truncation, single v_perm_b32
__device__ __forceinline__ unsigned int pk2t(float a, float b) {
  return __builtin_amdgcn_perm(__float_as_uint(b), __float_as_uint(a), 0x07060302u);
}
__device__ __forceinline__ float bfu(unsigned short u) {
  return __uint_as_float(((unsigned int)u) << 16);
}
__device__ __forceinline__ float bflo(unsigned int u) { return __uint_as_float(u << 16); }
__device__ __forceinline__ float bfhi(unsigned int u) { return __uint_as_float(u & 0xFFFF0000u); }

// ---------------- fused prep: LN->bf16 | castw | mmat | zero accg | zero Pbf pads+msum ----------------
__global__ void k_prep(const float* __restrict__ x, const float* __restrict__ g,
                       const float* __restrict__ b, unsigned short* __restrict__ lnbf,
                       const float* __restrict__ W, unsigned short* __restrict__ Wb,
                       const float* __restrict__ pw, const float* __restrict__ ow,
                       const float* __restrict__ ob, unsigned short* __restrict__ Mtb,
                       float* __restrict__ vbv,
                       float* __restrict__ accg, unsigned short* __restrict__ Pbf,
                       float* __restrict__ msum) {
  __shared__ float pr[256];
  __shared__ float red[256];
  const int bid = blockIdx.x;
  const int tid = threadIdx.x;
  if (bid < 256) {
    int wv = tid >> 6, lane = tid & 63;
    int r = bid * 4 + wv;
    float4 v = ((const float4*)(x + (size_t)r * CDIM))[lane];
    float s = v.x + v.y + v.z + v.w;
    float q = v.x * v.x + v.y * v.y + v.z * v.z + v.w * v.w;
    #pragma unroll
    for (int m = 32; m >= 1; m >>= 1) { s += __shfl_xor(s, m); q += __shfl_xor(q, m); }
    float mu = s * (1.0f / 256.0f);
    float var = q * (1.0f / 256.0f) - mu * mu;
    float rs = rsqrtf(var + 1e-5f);
    float4 gg = ((const float4*)g)[lane];
    float4 bb = ((const float4*)b)[lane];
    uint2 o;
    o.x = (unsigned int)bfr((v.x - mu) * rs * gg.x + bb.x) |
          ((unsigned int)bfr((v.y - mu) * rs * gg.y + bb.y) << 16);
    o.y = (unsigned int)bfr((v.z - mu) * rs * gg.z + bb.z) |
          ((unsigned int)bfr((v.w - mu) * rs * gg.w + bb.w) << 16);
    ((uint2*)(lnbf + (size_t)r * CDIM))[lane] = o;
  } else if (bid < 352) {
    int i = (bid - 256) * 256 + tid;
    const float4* src = (const float4*)W;
    float4 a = src[2 * i], c = src[2 * i + 1];
    uint4 o;
    o.x = (unsigned int)bfr(a.x) | ((unsigned int)bfr(a.y) << 16);
    o.y = (unsigned int)bfr(a.z) | ((unsigned int)bfr(a.w) << 16);
    o.z = (unsigned int)bfr(c.x) | ((unsigned int)bfr(c.y) << 16);
    o.w = (unsigned int)bfr(c.z) | ((unsigned int)bfr(c.w) << 16);
    ((uint4*)Wb)[i] = o;
  } else if (bid < 608) {
    const int e = bid - 352;
    pr[tid] = pw[(size_t)e * CDIM + tid];
    __syncthreads();
    float a0 = 0.f, a1 = 0.f, a2 = 0.f, a3 = 0.f;
    for (int m = 0; m < 256; m += 4) {
      a0 += pr[m] * ow[(size_t)m * CDIM + tid];
      a1 += pr[m + 1] * ow[(size_t)(m + 1) * CDIM + tid];
      a2 += pr[m + 2] * ow[(size_t)(m + 2) * CDIM + tid];
      a3 += pr[m + 3] * ow[(size_t)(m + 3) * CDIM + tid];
    }
    Mtb[(size_t)e * CDIM + tid] = bfr((a0 + a1) + (a2 + a3));
    red[tid] = pr[tid] * ob[tid];
    __syncthreads();
    for (int s = 128; s > 0; s >>= 1) { if (tid < s) red[tid] += red[tid + s]; __syncthreads(); }
    if (tid == 0) vbv[e] = red[0];
  } else if (bid < 624) {
    uint4 zz = make_uint4(0, 0, 0, 0);
    for (int i = (bid - 608) * 256 + tid; i < 147200; i += 16 * 256)
      ((uint4*)accg)[i] = zz;
  } else {
    uint4 zz = make_uint4(0, 0, 0, 0);
    for (int i = (bid - 624) * 256 + tid; i < 12096; i += 16 * 256) {
      int idx = (i < 6048) ? i : (104352 + (i - 6048));
      ((uint4*)Pbf)[idx] = zz;
    }
    if (bid == 624 && tid < 64) ((float4*)msum)[tid] = make_float4(0.f, 0.f, 0.f, 0.f);
  }
}

// ---------------- P projection via MFMA: 96 blocks, LDS-staged coalesced stores ----------------
__launch_bounds__(512, 1)
__global__ void k_proj(const unsigned short* __restrict__ lnbf,
                       const unsigned short* __restrict__ Wb,
                       unsigned short* __restrict__ Pbf) {
  __shared__ __align__(16) unsigned short Ps[64 * 128];   // 16 KB staging tile
  const int tid = threadIdx.x;
  const int lane = tid & 63, wv = tid >> 6;
  const int li16 = lane & 15, q4 = lane >> 4;
  const int ws = wv & 1, we = wv >> 1;        // 2 s-halves x 4 e-slices
  const int sbase = blockIdx.x * 64;          // 16 s-tiles of 64 rows
  const int ebase = blockIdx.y * 128;         // 6 e-tiles of 128
  const int s0 = sbase + ws * 32;
  const int e0 = ebase + we * 32;

  f32x4 acc[2][2];
  #pragma unroll
  for (int it = 0; it < 2; ++it)
    #pragma unroll
    for (int et = 0; et < 2; ++et) acc[it][et] = (f32x4){0.f, 0.f, 0.f, 0.f};

  #pragma unroll
  for (int ks = 0; ks < 8; ++ks) {
    bf16x8 Af[2], Bf[2];
    #pragma unroll
    for (int it = 0; it < 2; ++it)
      Af[it] = *(const bf16x8*)(lnbf + (size_t)(s0 + 16 * it + li16) * 256 + ks * 32 + q4 * 8);
    #pragma unroll
    for (int et = 0; et < 2; ++et)
      Bf[et] = *(const bf16x8*)(Wb + (size_t)(e0 + 16 * et + li16) * 256 + ks * 32 + q4 * 8);
    #pragma unroll
    for (int it = 0; it < 2; ++it)
      #pragma unroll
      for (int et = 0; et < 2; ++et)
        acc[it][et] = __builtin_amdgcn_mfma_f32_16x16x32_bf16(Af[it], Bf[et], acc[it][et], 0, 0, 0);
  }
  // scatter into LDS tile (local coords)
  #pragma unroll
  for (int it = 0; it < 2; ++it)
    #pragma unroll
    for (int et = 0; et < 2; ++et)
      #pragma unroll
      for (int r = 0; r < 4; ++r) {
        int lr = ws * 32 + 16 * it + 4 * q4 + r;
        int lc = we * 32 + 16 * et + li16;
        Ps[lr * 128 + lc] = bfr(acc[it][et][r]);
      }
  __syncthreads();
  // coalesced copy out: 64 rows x 128 u16 = 1024 uint4 chunks
  for (int i = tid; i < 1024; i += 512) {
    int r = i >> 4, c = (i & 15) * 8;
    *(uint4*)(Pbf + (size_t)(PADL + sbase + r) * 768 + ebase + c) = *(uint4*)&Ps[r * 128 + c];
  }
}

// ---------------- V' staging (512 thr): V'[j][d]=E(j)*h_j*Pv; row 64=E(j) ----------------
__device__ __forceinline__ void stage_v(const unsigned short* __restrict__ Pbf,
                                        unsigned short* vt, int v, int hd,
                                        int l0, int w, int tid,
                                        const float* __restrict__ bB,
                                        const float* __restrict__ hth) {
  const int jp = tid & 63;
  const int dg = tid >> 6;         // 0..7
  const int j0 = 2 * jp;
  const int p0 = w + j0;
  int row0 = prow(v, l0 + w + j0);
  int row1 = prow(v, l0 + w + j0 + 1);
  uint4 a = *(const uint4*)(Pbf + (size_t)row0 * 768 + 512 + hd * 64 + dg * 8);
  uint4 b = *(const uint4*)(Pbf + (size_t)row1 * 768 + 512 + hd * 64 + dg * 8);
  float h0 = hth[j0], h1 = hth[j0 + 1];
  float e0 = __expf(h0 * bB[p0] * 0.125f);
  float e1 = __expf(h1 * bB[p0 + 1] * 0.125f);
  float f0 = e0 * h0, f1 = e1 * h1;
  unsigned int av[4] = {a.x, a.y, a.z, a.w};
  unsigned int bv[4] = {b.x, b.y, b.z, b.w};
  #pragma unroll
  for (int q = 0; q < 4; ++q) {
    int d0 = dg * 8 + 2 * q;
    unsigned int w0 = pk2t(f0 * bflo(av[q]), f1 * bflo(bv[q]));
    unsigned int w1 = pk2t(f0 * bfhi(av[q]), f1 * bfhi(bv[q]));
    *(unsigned int*)&vt[d0 * 128 + (j0 ^ ((d0 & 7) << 3))] = w0;
    *(unsigned int*)&vt[(d0 + 1) * 128 + (j0 ^ (((d0 + 1) & 7) << 3))] = w1;
  }
  if (tid < 64) {   // E row at d=64 (swizzle (64&7)<<3 = 0)
    *(unsigned int*)&vt[64 * 128 + j0] = pk2t(e0, e1);
  }
}

// ---------------- MFMA attention (round-9 structure, proven 93.7 us) ----------------
__launch_bounds__(512, 2)
__global__ void k_attn(const unsigned short* __restrict__ Pbf, const float* __restrict__ ipb,
                       float* __restrict__ accg) {
  __shared__ __align__(16) unsigned short Pq[159 * 64];    // swizzle blk d^((t&7)<<3)
  __shared__ __align__(16) unsigned short Pk[159 * 64];
  __shared__ __align__(16) unsigned short Vt[2][80 * 128]; // rows 0..63 V', 64 E, 65..79 zero
  __shared__ __align__(16) unsigned short Ab[128 * 128];   // A''=exp, swizzle j^((i&7)<<3)
  __shared__ __align__(16) float accs[159 * 68];
  __shared__ float hth[128];
  __shared__ float bB[160];
  __shared__ float bqS[64];

  const int strip = blockIdx.x, hd = blockIdx.y, v = blockIdx.z;
  const int l0 = strip * SW;
  const int nw = (SW < LWIN - l0) ? SW : (LWIN - l0);
  const int span = nw - 1 + WIN_;
  const int tid = threadIdx.x;
  const int lane = tid & 63, wv = tid >> 6;
  const int li16 = lane & 15, q4 = lane >> 4;
  const int iw = 16 * wv + li16;

  for (int i = tid; i < 159 * 68; i += 512) accs[i] = 0.0f;
  if (tid < 128) hth[tid] = hannf(tid);
  if (tid < 64) bqS[tid] = ipb[hd * 64 + tid];
  for (int i = tid; i < span * 8; i += 512) {
    int t = i >> 3, dg = i & 7;
    int row = prow(v, l0 + t);
    const unsigned short* src = Pbf + (size_t)row * 768 + hd * 64;
    uint4 q = *(const uint4*)(src + dg * 8);
    uint4 k = *(const uint4*)(src + 256 + dg * 8);
    int off = (dg * 8) ^ ((t & 7) << 3);
    *(uint4*)&Pq[t * 64 + off] = q;
    *(uint4*)&Pk[t * 64 + off] = k;
  }
  // zero Vt pad rows 65..79 of both buffers (240 uint4 each)
  {
    uint4 zz = make_uint4(0, 0, 0, 0);
    for (int i = tid; i < 480; i += 512) {
      int bidx = i / 240, k = i % 240;
      *(uint4*)&Vt[bidx][65 * 128 + k * 8] = zz;
    }
  }
  __syncthreads();

  // bias-dot array b(t) = bq·Pk(t)
  for (int p = tid; p < span; p += 512) {
    float b = 0.0f;
    int sw = (p & 7) << 3;
    for (int d = 0; d < 64; ++d) b += bqS[d] * bfu(Pk[p * 64 + (d ^ sw)]);
    bB[p] = b;
  }
  __syncthreads();          // bB ready before stage_v reads it
  stage_v(Pbf, &Vt[0][0], v, hd, l0, 0, tid, bB, hth);
  __syncthreads();

  // per-thread hh[m] = h_i * h_j(m) / 8
  float hh[32];
  {
    const float h_i = hth[iw];
    #pragma unroll
    for (int tj = 0; tj < 8; ++tj)
      #pragma unroll
      for (int r = 0; r < 4; ++r)
        hh[tj * 4 + r] = h_i * hth[16 * tj + 4 * q4 + r] * 0.125f;
  }

  #pragma unroll 1
  for (int w = 0; w < nw; ++w) {
    // ---- S^T[j][i] = Pk[w+j]·Pq[w+i] (raw Gram) ----
    bf16x8 Qf[2];
    {
      int t = w + iw, sw = (t & 7) << 3;
      Qf[0] = *(bf16x8*)&Pq[t * 64 + ((8 * q4) ^ sw)];
      Qf[1] = *(bf16x8*)&Pq[t * 64 + ((32 + 8 * q4) ^ sw)];
    }
    f32x4 S[8];
    #pragma unroll
    for (int tj = 0; tj < 8; ++tj) S[tj] = (f32x4){0.f, 0.f, 0.f, 0.f};
    #pragma unroll
    for (int tj = 0; tj < 8; ++tj) {
      int t = w + 16 * tj + li16, sw = (t & 7) << 3;
      bf16x8 Kf0 = *(bf16x8*)&Pk[t * 64 + ((8 * q4) ^ sw)];
      bf16x8 Kf1 = *(bf16x8*)&Pk[t * 64 + ((32 + 8 * q4) ^ sw)];
      S[tj] = __builtin_amdgcn_mfma_f32_16x16x32_bf16(Kf0, Qf[0], S[tj], 0, 0, 0);
      S[tj] = __builtin_amdgcn_mfma_f32_16x16x32_bf16(Kf1, Qf[1], S[tj], 0, 0, 0);
    }

    // ---- A'' = exp(hh*S)  (|hh*S| small; E/h_j folded into V') ----
    #pragma unroll
    for (int tj = 0; tj < 8; ++tj)
      #pragma unroll
      for (int r = 0; r < 4; ++r)
        S[tj][r] = __expf(hh[tj * 4 + r] * S[tj][r]);

    // ---- pack raw exp into Ab (wave-private rows) ----
    {
      int sw = (iw & 7) << 3;
      #pragma unroll
      for (int tj = 0; tj < 8; ++tj) {
        uint2 o;
        o.x = pk2t(S[tj][0], S[tj][1]);
        o.y = pk2t(S[tj][2], S[tj][3]);
        *(uint2*)&Ab[iw * 128 + ((16 * tj + 4 * q4) ^ sw)] = o;
      }
    }

    // ---- O'^T[d][i] = sum_j V'[d][j]*A''[i][j]; tile mt=4 yields normalizer (E row) ----
    f32x4 O[5];
    #pragma unroll
    for (int mt = 0; mt < 5; ++mt) O[mt] = (f32x4){0.f, 0.f, 0.f, 0.f};
    const unsigned short* vt = &Vt[w & 1][0];
    {
      int swi = (iw & 7) << 3;
      #pragma unroll
      for (int ks = 0; ks < 4; ++ks) {
        bf16x8 Bf = *(bf16x8*)&Ab[iw * 128 + ((32 * ks + 8 * q4) ^ swi)];
        #pragma unroll
        for (int mt = 0; mt < 5; ++mt) {
          int d = 16 * mt + li16;
          bf16x8 Af = *(bf16x8*)&vt[d * 128 + ((32 * ks + 8 * q4) ^ ((d & 7) << 3))];
          O[mt] = __builtin_amdgcn_mfma_f32_16x16x32_bf16(Af, Bf, O[mt], 0, 0, 0);
        }
      }
    }

    // ---- normalizer: row 64 value lives at lane li16 (q4=0), reg 0 of tile 4 ----
    float nn = __shfl(O[4][0], li16);
    float sc = 1.0f / nn;

    // ---- accumulate O^T * sc (vector RMW, race-free ownership) ----
    {
      float* arow = &accs[(w + iw) * 68];
      #pragma unroll
      for (int mt = 0; mt < 4; ++mt) {
        int c = 16 * mt + 4 * q4;
        float4 cur = *(float4*)&arow[c];
        cur.x += O[mt][0] * sc; cur.y += O[mt][1] * sc;
        cur.z += O[mt][2] * sc; cur.w += O[mt][3] * sc;
        *(float4*)&arow[c] = cur;
      }
    }

    if (w + 1 < nw) stage_v(Pbf, &Vt[(w + 1) & 1][0], v, hd, l0, w + 1, tid, bB, hth);
    __syncthreads();
  }

  // ---- epilogue: + cnt*bv, atomic into global ----
  float* av = accg + (size_t)v * TPAD * CDIM;
  for (int i = tid; i < span * 64; i += 512) {
    int p = i >> 6, dd = i & 63;
    int lo = p - 127; if (lo < 0) lo = 0;
    int hi = p; if (hi > nw - 1) hi = nw - 1;
    float cnt = (float)(hi - lo + 1);
    float bvd = ipb[512 + hd * 64 + dd];
    atomicAdd(&av[(size_t)(l0 + p) * CDIM + hd * 64 + dd],
              accs[p * 68 + dd] + cnt * bvd);
  }
}

// ---------------- combine variants + merged projection (MFMA, 32-row tiles, 64 blocks) ----------------
__launch_bounds__(512, 2)
__global__ void k_comb(const float* __restrict__ accg, const unsigned short* __restrict__ Mtb,
                       const float* __restrict__ vbv, const float* __restrict__ pb,
                       float* __restrict__ z, float* __restrict__ msum) {
  __shared__ __align__(16) unsigned short Ub[32 * 264];
  __shared__ float cfA[32], cfB[32], bscL[32];
  __shared__ float msB[128];
  const int tid = threadIdx.x;
  const int lane = tid & 63, wv = tid >> 6;
  const int li16 = lane & 15, q4 = lane >> 4;
  const int t0 = blockIdx.x * 32;
  const int e0 = blockIdx.y * 128;

  if (tid < 32) {
    int s = t0 + tid;
    float c0 = countf(PADL + s);
    float c1 = countf(PADL + ((s + 64) & (TLEN - 1)));
    float fA = 0.5f / (c0 + 1e-6f), fB = 0.5f / (c1 + 1e-6f);
    cfA[tid] = fA; cfB[tid] = fB;
    bscL[tid] = c0 * fA + c1 * fB;
  }
  if (tid < 128) msB[tid] = 0.0f;
  __syncthreads();

  // build u-tile: u = 0.5*(a0/c0 + a1/c1), bf16
  for (int i = tid; i < 32 * 128; i += 512) {
    int rr = i >> 7, c2 = (i & 127) * 2;
    int s = t0 + rr;
    int s1 = (s + 64) & (TLEN - 1);
    float2 a0 = *(const float2*)&accg[(size_t)(PADL + s) * CDIM + c2];
    float2 a1 = *(const float2*)&accg[(size_t)TPAD * CDIM + (size_t)(PADL + s1) * CDIM + c2];
    float fA = cfA[rr], fB = cfB[rr];
    *(unsigned int*)&Ub[rr * 264 + c2] =
        pk2t(a0.x * fA + a1.x * fB, a0.y * fA + a1.y * fB);
  }
  __syncthreads();

  // GEMM: z[t][e] = sum_c u[t][c] * M[e][c]; wave wv owns e-slice of 16
  f32x4 acc[2];
  acc[0] = (f32x4){0.f, 0.f, 0.f, 0.f};
  acc[1] = (f32x4){0.f, 0.f, 0.f, 0.f};
  #pragma unroll
  for (int ks = 0; ks < 8; ++ks) {
    bf16x8 Bf = *(const bf16x8*)(Mtb + (size_t)(e0 + wv * 16 + li16) * 256 + ks * 32 + q4 * 8);
    #pragma unroll
    for (int it = 0; it < 2; ++it) {
      bf16x8 Af = *(bf16x8*)&Ub[(16 * it + li16) * 264 + ks * 32 + q4 * 8];
      acc[it] = __builtin_amdgcn_mfma_f32_16x16x32_bf16(Af, Bf, acc[it], 0, 0, 0);
    }
  }

  // epilogue + msum
  {
    int e = e0 + wv * 16 + li16;
    float vbe = vbv[e], pbe = pb[e];
    float part = 0.0f;
    #pragma unroll
    for (int it = 0; it < 2; ++it)
      #pragma unroll
      for (int r = 0; r < 4; ++r) {
        int rloc = 16 * it + 4 * q4 + r;
        float val = acc[it][r] + bscL[rloc] * vbe + pbe;
        z[(size_t)(t0 + rloc) * CDIM + e] = val;
        part += val;
      }
    atomicAdd(&msB[e - e0], part);
  }
  __syncthreads();
  if (tid < 128) atomicAdd(&msum[e0 + tid], msB[tid]);
}

// ---------------- fused SE gate + residual ----------------
__global__ void k_finalse(const float* __restrict__ x, const float* __restrict__ z,
                          const float* __restrict__ msum, const float* __restrict__ w1,
                          const float* __restrict__ w2, float* __restrict__ out) {
  __shared__ float red2[16][4];
  __shared__ float s1[16];
  __shared__ float gateS[256];
  int tid = threadIdx.x;
  int lane = tid & 63, wv = tid >> 6;
  float sm = msum[tid] * (1.0f / 1024.0f);
  #pragma unroll
  for (int r = 0; r < 16; ++r) {
    float v = sm * w1[(size_t)r * 256 + tid];
    #pragma unroll
    for (int m = 32; m >= 1; m >>= 1) v += __shfl_xor(v, m);
    if (lane == 0) red2[r][wv] = v;
  }
  __syncthreads();
  if (tid < 16) {
    float a = red2[tid][0] + red2[tid][1] + red2[tid][2] + red2[tid][3];
    s1[tid] = fmaxf(a, 0.0f);
  }
  __syncthreads();
  float gacc = 0.0f;
  #pragma unroll
  for (int i = 0; i < 16; ++i) gacc += s1[i] * w2[(size_t)tid * 16 + i];
  gateS[tid] = 1.0f / (1.0f + __expf(-gacc));
  __syncthreads();
  int i = blockIdx.x * 256 + tid;
  float4 xv = ((const float4*)x)[i];
  float4 zv = ((const float4*)z)[i];
  float4 gv = ((const float4*)gateS)[i & 63];
  float4 o;
  o.x = xv.x + zv.x * gv.x;
  o.y = xv.y + zv.y * gv.y;
  o.z = xv.z + zv.z * gv.z;
  o.w = xv.w + zv.w * gv.w;
  ((float4*)out)[i] = o;
}

extern "C" void kernel_launch(void* const* d_in, const int* in_sizes, int n_in,
                              void* d_out, int out_size, void* d_ws, size_t ws_size,
                              hipStream_t stream) {
  const float* x   = (const float*)d_in[0];
  const float* lng = (const float*)d_in[1];
  const float* lnb = (const float*)d_in[2];
  const float* ipw = (const float*)d_in[3];
  const float* ipb = (const float*)d_in[4];
  const float* ow  = (const float*)d_in[5];
  const float* ob  = (const float*)d_in[6];
  const float* pw  = (const float*)d_in[7];
  const float* pb  = (const float*)d_in[8];
  const float* w1  = (const float*)d_in[9];
  const float* w2  = (const float*)d_in[10];
  float* out = (float*)d_out;

  float* ws = (float*)d_ws;
  unsigned short* lnbf = (unsigned short*)ws;             // 131072 f
  unsigned short* Wb   = (unsigned short*)(ws + 131072);  // 98304 f
  unsigned short* Pbf  = (unsigned short*)(ws + 229376);  // 441600 f
  float* accg = ws + 229376 + 441600;                     // 588800 f
  unsigned short* Mtb = (unsigned short*)(accg + 588800); // 32768 f
  float* vbv  = accg + 588800 + 32768;                    // 256
  float* z    = vbv + 256;                                // 262144
  float* msum = z + 262144;                               // 256

  k_prep<<<dim3(640), dim3(256), 0, stream>>>(x, lng, lnb, lnbf, ipw, Wb,
                                              pw, ow, ob, Mtb, vbv, accg, Pbf, msum);
  k_proj<<<dim3(16, 6), dim3(512), 0, stream>>>(lnbf, Wb, Pbf);
  k_attn<<<dim3(32, NHEAD, 2), dim3(512), 0, stream>>>(Pbf, ipb, accg);
  k_comb<<<dim3(32, 2), dim3(512), 0, stream>>>(accg, Mtb, vbv, pb, z, msum);
  k_finalse<<<dim3(256), dim3(256), 0, stream>>>(x, z, msum, w1, w2, out);
}

// Round 13
// 186.290 us; speedup vs baseline: 1.1806x; 1.0336x over previous
//
#include <hip/hip_runtime.h>

#define TLEN 1024
#define CDIM 256
#define NHEAD 4
#define HD 64
#define WIN_ 128
#define PADL 63
#define LWIN 1023
#define TPAD 1150
#define SW 32        // windows per strip: 32 strips x 4 heads x 2 variants = 256 blocks

typedef __attribute__((ext_vector_type(8))) short bf16x8;
typedef __attribute__((ext_vector_type(4))) float f32x4;

__device__ __forceinline__ int prow(int v, int t) {
  if (v == 0) return t;
  if (t < PADL || t >= PADL + TLEN) return t;
  int s = t - PADL;
  s = (s + (TLEN - 64)) & (TLEN - 1);   // roll(x, +64)
  return PADL + s;
}

__device__ __forceinline__ float hannf(int j) {
  return 0.5f * (1.0f - __cosf(6.283185307179586f * (float)j / 127.0f));
}

__device__ __forceinline__ float countf(int t) {
  int lo = t - 127; if (lo < 0) lo = 0;
  int hi = t;       if (hi > LWIN - 1) hi = LWIN - 1;
  return (float)(hi - lo + 1);
}

__device__ __forceinline__ unsigned short bfr(float f) {  // fp32 -> bf16 RTNE
  unsigned int u = __float_as_uint(f);
  u += 0x7FFFu + ((u >> 16) & 1u);
  return (unsigned short)(u >> 16);
}
// pack two f32 -> bf16x2 by truncation, single v_perm_b32
__device__ __forceinline__ unsigned int pk2t(float a, float b) {
  return __builtin_amdgcn_perm(__float_as_uint(b), __float_as_uint(a), 0x07060302u);
}
__device__ __forceinline__ float bfu(unsigned short u) {
  return __uint_as_float(((unsigned int)u) << 16);
}
__device__ __forceinline__ float bflo(unsigned int u) { return __uint_as_float(u << 16); }
__device__ __forceinline__ float bfhi(unsigned int u) { return __uint_as_float(u & 0xFFFF0000u); }

#define AL16(h, l) ((((unsigned int)(l)) >> 16) | (((unsigned int)(h)) << 16))

// ---------------- fused prep: LN->bf16 | castw | mmat | zero accg | zero Pbf pads+msum ----------------
__global__ void k_prep(const float* __restrict__ x, const float* __restrict__ g,
                       const float* __restrict__ b, unsigned short* __restrict__ lnbf,
                       const float* __restrict__ W, unsigned short* __restrict__ Wb,
                       const float* __restrict__ pw, const float* __restrict__ ow,
                       const float* __restrict__ ob, unsigned short* __restrict__ Mtb,
                       float* __restrict__ vbv,
                       float* __restrict__ accg, unsigned short* __restrict__ Pbf,
                       float* __restrict__ msum) {
  __shared__ float pr[256];
  __shared__ float red[256];
  const int bid = blockIdx.x;
  const int tid = threadIdx.x;
  if (bid < 256) {
    int wv = tid >> 6, lane = tid & 63;
    int r = bid * 4 + wv;
    float4 v = ((const float4*)(x + (size_t)r * CDIM))[lane];
    float s = v.x + v.y + v.z + v.w;
    float q = v.x * v.x + v.y * v.y + v.z * v.z + v.w * v.w;
    #pragma unroll
    for (int m = 32; m >= 1; m >>= 1) { s += __shfl_xor(s, m); q += __shfl_xor(q, m); }
    float mu = s * (1.0f / 256.0f);
    float var = q * (1.0f / 256.0f) - mu * mu;
    float rs = rsqrtf(var + 1e-5f);
    float4 gg = ((const float4*)g)[lane];
    float4 bb = ((const float4*)b)[lane];
    uint2 o;
    o.x = (unsigned int)bfr((v.x - mu) * rs * gg.x + bb.x) |
          ((unsigned int)bfr((v.y - mu) * rs * gg.y + bb.y) << 16);
    o.y = (unsigned int)bfr((v.z - mu) * rs * gg.z + bb.z) |
          ((unsigned int)bfr((v.w - mu) * rs * gg.w + bb.w) << 16);
    ((uint2*)(lnbf + (size_t)r * CDIM))[lane] = o;
  } else if (bid < 352) {
    int i = (bid - 256) * 256 + tid;
    const float4* src = (const float4*)W;
    float4 a = src[2 * i], c = src[2 * i + 1];
    uint4 o;
    o.x = (unsigned int)bfr(a.x) | ((unsigned int)bfr(a.y) << 16);
    o.y = (unsigned int)bfr(a.z) | ((unsigned int)bfr(a.w) << 16);
    o.z = (unsigned int)bfr(c.x) | ((unsigned int)bfr(c.y) << 16);
    o.w = (unsigned int)bfr(c.z) | ((unsigned int)bfr(c.w) << 16);
    ((uint4*)Wb)[i] = o;
  } else if (bid < 608) {
    const int e = bid - 352;
    pr[tid] = pw[(size_t)e * CDIM + tid];
    __syncthreads();
    float a0 = 0.f, a1 = 0.f, a2 = 0.f, a3 = 0.f;
    for (int m = 0; m < 256; m += 4) {
      a0 += pr[m] * ow[(size_t)m * CDIM + tid];
      a1 += pr[m + 1] * ow[(size_t)(m + 1) * CDIM + tid];
      a2 += pr[m + 2] * ow[(size_t)(m + 2) * CDIM + tid];
      a3 += pr[m + 3] * ow[(size_t)(m + 3) * CDIM + tid];
    }
    Mtb[(size_t)e * CDIM + tid] = bfr((a0 + a1) + (a2 + a3));
    red[tid] = pr[tid] * ob[tid];
    __syncthreads();
    for (int s = 128; s > 0; s >>= 1) { if (tid < s) red[tid] += red[tid + s]; __syncthreads(); }
    if (tid == 0) vbv[e] = red[0];
  } else if (bid < 624) {
    uint4 zz = make_uint4(0, 0, 0, 0);
    for (int i = (bid - 608) * 256 + tid; i < 147200; i += 16 * 256)
      ((uint4*)accg)[i] = zz;
  } else {
    uint4 zz = make_uint4(0, 0, 0, 0);
    for (int i = (bid - 624) * 256 + tid; i < 12096; i += 16 * 256) {
      int idx = (i < 6048) ? i : (104352 + (i - 6048));
      ((uint4*)Pbf)[idx] = zz;
    }
    if (bid == 624 && tid < 64) ((float4*)msum)[tid] = make_float4(0.f, 0.f, 0.f, 0.f);
  }
}

// ---------------- P projection via MFMA: 96 blocks, LDS-staged coalesced stores ----------------
__launch_bounds__(512, 1)
__global__ void k_proj(const unsigned short* __restrict__ lnbf,
                       const unsigned short* __restrict__ Wb,
                       unsigned short* __restrict__ Pbf) {
  __shared__ __align__(16) unsigned short Ps[64 * 128];
  const int tid = threadIdx.x;
  const int lane = tid & 63, wv = tid >> 6;
  const int li16 = lane & 15, q4 = lane >> 4;
  const int ws = wv & 1, we = wv >> 1;
  const int sbase = blockIdx.x * 64;
  const int ebase = blockIdx.y * 128;
  const int s0 = sbase + ws * 32;
  const int e0 = ebase + we * 32;

  f32x4 acc[2][2];
  #pragma unroll
  for (int it = 0; it < 2; ++it)
    #pragma unroll
    for (int et = 0; et < 2; ++et) acc[it][et] = (f32x4){0.f, 0.f, 0.f, 0.f};

  #pragma unroll
  for (int ks = 0; ks < 8; ++ks) {
    bf16x8 Af[2], Bf[2];
    #pragma unroll
    for (int it = 0; it < 2; ++it)
      Af[it] = *(const bf16x8*)(lnbf + (size_t)(s0 + 16 * it + li16) * 256 + ks * 32 + q4 * 8);
    #pragma unroll
    for (int et = 0; et < 2; ++et)
      Bf[et] = *(const bf16x8*)(Wb + (size_t)(e0 + 16 * et + li16) * 256 + ks * 32 + q4 * 8);
    #pragma unroll
    for (int it = 0; it < 2; ++it)
      #pragma unroll
      for (int et = 0; et < 2; ++et)
        acc[it][et] = __builtin_amdgcn_mfma_f32_16x16x32_bf16(Af[it], Bf[et], acc[it][et], 0, 0, 0);
  }
  #pragma unroll
  for (int it = 0; it < 2; ++it)
    #pragma unroll
    for (int et = 0; et < 2; ++et)
      #pragma unroll
      for (int r = 0; r < 4; ++r) {
        int lr = ws * 32 + 16 * it + 4 * q4 + r;
        int lc = we * 32 + 16 * et + li16;
        Ps[lr * 128 + lc] = bfr(acc[it][et][r]);
      }
  __syncthreads();
  for (int i = tid; i < 1024; i += 512) {
    int r = i >> 4, c = (i & 15) * 8;
    *(uint4*)(Pbf + (size_t)(PADL + sbase + r) * 768 + ebase + c) = *(uint4*)&Ps[r * 128 + c];
  }
}

// ---------------- V' staging (512 thr): V'[j][d]=E(j)*h_j*Pv; row 64=E(j) ----------------
__device__ __forceinline__ void stage_v(const unsigned short* __restrict__ Pbf,
                                        unsigned short* vt, int v, int hd,
                                        int l0, int w, int tid,
                                        const float* __restrict__ bB,
                                        const float* __restrict__ hth) {
  const int jp = tid & 63;
  const int dg = tid >> 6;         // 0..7
  const int j0 = 2 * jp;
  const int p0 = w + j0;
  int row0 = prow(v, l0 + w + j0);
  int row1 = prow(v, l0 + w + j0 + 1);
  uint4 a = *(const uint4*)(Pbf + (size_t)row0 * 768 + 512 + hd * 64 + dg * 8);
  uint4 b = *(const uint4*)(Pbf + (size_t)row1 * 768 + 512 + hd * 64 + dg * 8);
  float h0 = hth[j0], h1 = hth[j0 + 1];
  float e0 = __expf(h0 * bB[p0] * 0.125f);
  float e1 = __expf(h1 * bB[p0 + 1] * 0.125f);
  float f0 = e0 * h0, f1 = e1 * h1;
  unsigned int av[4] = {a.x, a.y, a.z, a.w};
  unsigned int bv[4] = {b.x, b.y, b.z, b.w};
  #pragma unroll
  for (int q = 0; q < 4; ++q) {
    int d0 = dg * 8 + 2 * q;
    unsigned int w0 = pk2t(f0 * bflo(av[q]), f1 * bflo(bv[q]));
    unsigned int w1 = pk2t(f0 * bfhi(av[q]), f1 * bfhi(bv[q]));
    *(unsigned int*)&vt[d0 * 128 + (j0 ^ ((d0 & 7) << 3))] = w0;
    *(unsigned int*)&vt[(d0 + 1) * 128 + (j0 ^ (((d0 + 1) & 7) << 3))] = w1;
  }
  if (tid < 64) {   // E row at d=64 (swizzle (64&7)<<3 = 0)
    *(unsigned int*)&vt[64 * 128 + j0] = pk2t(e0, e1);
  }
}

// ---------------- MFMA attention: strip Gram-band cache, direct-register A ----------------
__launch_bounds__(512, 2)
__global__ void k_attn(const unsigned short* __restrict__ Pbf, const float* __restrict__ ipb,
                       float* __restrict__ accg) {
  __shared__ __align__(16) unsigned short band[160 * 168]; // G[a][b] bf16, stride 168 (16B-aligned rows)
  __shared__ __align__(16) unsigned short Vt[2][80 * 128]; // rows 0..63 V', 64 E, 65..79 zero
  __shared__ __align__(16) unsigned char uni[159 * 68 * 4]; // union: Pq+Pk (init) -> accs (loop)
  __shared__ float hth[128];
  __shared__ float bB[160];
  __shared__ float bqS[64];

  unsigned short* Pq = (unsigned short*)uni;       // 159*64 u16
  unsigned short* Pk = Pq + 159 * 64;              // 159*64 u16 (total 40704 B < 43248 B)
  float* accs = (float*)uni;                       // 159*68 f32

  const int strip = blockIdx.x, hd = blockIdx.y, v = blockIdx.z;
  const int l0 = strip * SW;
  const int nw = (SW < LWIN - l0) ? SW : (LWIN - l0);
  const int span = nw - 1 + WIN_;
  const int tid = threadIdx.x;
  const int lane = tid & 63, wv = tid >> 6;
  const int li16 = lane & 15, q4 = lane >> 4;
  const int iw = 16 * wv + li16;

  if (tid < 128) hth[tid] = hannf(tid);
  if (tid < 64) bqS[tid] = ipb[hd * 64 + tid];
  // stage raw Pq/Pk spans (swizzle blk d^((t&7)<<3))
  for (int i = tid; i < span * 8; i += 512) {
    int t = i >> 3, dg = i & 7;
    int row = prow(v, l0 + t);
    const unsigned short* src = Pbf + (size_t)row * 768 + hd * 64;
    uint4 q = *(const uint4*)(src + dg * 8);
    uint4 k = *(const uint4*)(src + 256 + dg * 8);
    int off = (dg * 8) ^ ((t & 7) << 3);
    *(uint4*)&Pq[t * 64 + off] = q;
    *(uint4*)&Pk[t * 64 + off] = k;
  }
  // zero Vt pad rows 65..79 of both buffers
  {
    uint4 zz = make_uint4(0, 0, 0, 0);
    for (int i = tid; i < 480; i += 512) {
      int bidx = i / 240, k = i % 240;
      *(uint4*)&Vt[bidx][65 * 128 + k * 8] = zz;
    }
  }
  __syncthreads();

  // bias-dot array b(t) = bq·Pk(t)
  for (int p = tid; p < span; p += 512) {
    float b = 0.0f;
    int sw = (p & 7) << 3;
    for (int d = 0; d < 64; ++d) b += bqS[d] * bfu(Pk[p * 64 + (d ^ sw)]);
    bB[p] = b;
  }
  // ---- build Gram band: G[a][b] = Pq[a]·Pk[b], 10x10 tiles of 16x16, K=64 ----
  for (int tile = wv; tile < 100; tile += 8) {
    int ta = tile / 10, tb = tile - 10 * (tile / 10);
    int tqa = 16 * ta + li16, swq = (tqa & 7) << 3;
    bf16x8 Aq0 = *(bf16x8*)&Pq[tqa * 64 + ((8 * q4) ^ swq)];
    bf16x8 Aq1 = *(bf16x8*)&Pq[tqa * 64 + ((32 + 8 * q4) ^ swq)];
    int tkb = 16 * tb + li16, swk = (tkb & 7) << 3;
    bf16x8 Bk0 = *(bf16x8*)&Pk[tkb * 64 + ((8 * q4) ^ swk)];
    bf16x8 Bk1 = *(bf16x8*)&Pk[tkb * 64 + ((32 + 8 * q4) ^ swk)];
    f32x4 D = (f32x4){0.f, 0.f, 0.f, 0.f};
    D = __builtin_amdgcn_mfma_f32_16x16x32_bf16(Aq0, Bk0, D, 0, 0, 0);
    D = __builtin_amdgcn_mfma_f32_16x16x32_bf16(Aq1, Bk1, D, 0, 0, 0);
    // D[m=a][n=b]: a = 16ta+4q4+r, b = 16tb+li16
    #pragma unroll
    for (int r = 0; r < 4; ++r)
      band[(16 * ta + 4 * q4 + r) * 168 + 16 * tb + li16] = bfr(D[r]);
  }
  __syncthreads();   // band done; Pq/Pk dead

  // zero accs (overwrites Pq/Pk) + stage first V window
  for (int i = tid; i < 159 * 68; i += 512) accs[i] = 0.0f;
  stage_v(Pbf, &Vt[0][0], v, hd, l0, 0, tid, bB, hth);
  __syncthreads();

  // hh2[ks*8+jj] = h_i * h(32ks+8q4+jj) / 8
  float hh2[32];
  {
    const float h_i = hth[iw];
    #pragma unroll
    for (int ks = 0; ks < 4; ++ks)
      #pragma unroll
      for (int jj = 0; jj < 8; ++jj)
        hh2[ks * 8 + jj] = h_i * hth[32 * ks + 8 * q4 + jj] * 0.125f;
  }

  #pragma unroll 1
  for (int w = 0; w < nw; ++w) {
    const int m = w & 7;
    const unsigned short* brow = &band[(w + iw) * 168 + (w & ~7)];
    const unsigned short* vt = &Vt[w & 1][0];

    f32x4 O[5];
    #pragma unroll
    for (int mt = 0; mt < 5; ++mt) O[mt] = (f32x4){0.f, 0.f, 0.f, 0.f};

    #pragma unroll
    for (int ks = 0; ks < 4; ++ks) {
      // aligned 16-u16 window covering cols [w+32ks+8q4, +8)
      uint4 R0 = *(const uint4*)&brow[32 * ks + 8 * q4];
      uint4 R1 = *(const uint4*)&brow[32 * ks + 8 * q4 + 8];
      unsigned int d0 = R0.x, d1 = R0.y, d2 = R0.z, d3 = R0.w;
      unsigned int d4 = R1.x, d5 = R1.y, d6 = R1.z, d7 = R1.w;
      unsigned int o0, o1, o2, o3;
      switch (m) {   // wave-uniform branch
        case 0: o0 = d0; o1 = d1; o2 = d2; o3 = d3; break;
        case 1: o0 = AL16(d1, d0); o1 = AL16(d2, d1); o2 = AL16(d3, d2); o3 = AL16(d4, d3); break;
        case 2: o0 = d1; o1 = d2; o2 = d3; o3 = d4; break;
        case 3: o0 = AL16(d2, d1); o1 = AL16(d3, d2); o2 = AL16(d4, d3); o3 = AL16(d5, d4); break;
        case 4: o0 = d2; o1 = d3; o2 = d4; o3 = d5; break;
        case 5: o0 = AL16(d3, d2); o1 = AL16(d4, d3); o2 = AL16(d5, d4); o3 = AL16(d6, d5); break;
        case 6: o0 = d3; o1 = d4; o2 = d5; o3 = d6; break;
        default: o0 = AL16(d4, d3); o1 = AL16(d5, d4); o2 = AL16(d6, d5); o3 = AL16(d7, d6); break;
      }
      // A'' = exp(hh2 * G), packed directly as B-operand fragment
      float a0 = __expf(hh2[ks * 8 + 0] * bflo(o0));
      float a1 = __expf(hh2[ks * 8 + 1] * bfhi(o0));
      float a2 = __expf(hh2[ks * 8 + 2] * bflo(o1));
      float a3 = __expf(hh2[ks * 8 + 3] * bfhi(o1));
      float a4 = __expf(hh2[ks * 8 + 4] * bflo(o2));
      float a5 = __expf(hh2[ks * 8 + 5] * bfhi(o2));
      float a6 = __expf(hh2[ks * 8 + 6] * bflo(o3));
      float a7 = __expf(hh2[ks * 8 + 7] * bfhi(o3));
      union { uint4 u; bf16x8 f; } cvt;
      cvt.u.x = pk2t(a0, a1);
      cvt.u.y = pk2t(a2, a3);
      cvt.u.z = pk2t(a4, a5);
      cvt.u.w = pk2t(a6, a7);
      bf16x8 Bf = cvt.f;

      #pragma unroll
      for (int mt = 0; mt < 5; ++mt) {
        int d = 16 * mt + li16;
        bf16x8 Af = *(bf16x8*)&vt[d * 128 + ((32 * ks + 8 * q4) ^ ((d & 7) << 3))];
        O[mt] = __builtin_amdgcn_mfma_f32_16x16x32_bf16(Af, Bf, O[mt], 0, 0, 0);
      }
    }

    // normalizer: E row (d=64) value at q4=0, reg 0 of tile 4
    float nn = __shfl(O[4][0], li16);
    float sc = 1.0f / nn;

    // accumulate O^T * sc (vector RMW, race-free ownership)
    {
      float* arow = &accs[(w + iw) * 68];
      #pragma unroll
      for (int mt = 0; mt < 4; ++mt) {
        int c = 16 * mt + 4 * q4;
        float4 cur = *(float4*)&arow[c];
        cur.x += O[mt][0] * sc; cur.y += O[mt][1] * sc;
        cur.z += O[mt][2] * sc; cur.w += O[mt][3] * sc;
        *(float4*)&arow[c] = cur;
      }
    }

    if (w + 1 < nw) stage_v(Pbf, &Vt[(w + 1) & 1][0], v, hd, l0, w + 1, tid, bB, hth);
    __syncthreads();
  }

  // ---- epilogue: + cnt*bv, atomic into global ----
  float* av = accg + (size_t)v * TPAD * CDIM;
  for (int i = tid; i < span * 64; i += 512) {
    int p = i >> 6, dd = i & 63;
    int lo = p - 127; if (lo < 0) lo = 0;
    int hi = p; if (hi > nw - 1) hi = nw - 1;
    float cnt = (float)(hi - lo + 1);
    float bvd = ipb[512 + hd * 64 + dd];
    atomicAdd(&av[(size_t)(l0 + p) * CDIM + hd * 64 + dd],
              accs[p * 68 + dd] + cnt * bvd);
  }
}

// ---------------- combine variants + merged projection (MFMA, 32-row tiles, 64 blocks) ----------------
__launch_bounds__(512, 2)
__global__ void k_comb(const float* __restrict__ accg, const unsigned short* __restrict__ Mtb,
                       const float* __restrict__ vbv, const float* __restrict__ pb,
                       float* __restrict__ z, float* __restrict__ msum) {
  __shared__ __align__(16) unsigned short Ub[32 * 264];
  __shared__ float cfA[32], cfB[32], bscL[32];
  __shared__ float msB[128];
  const int tid = threadIdx.x;
  const int lane = tid & 63, wv = tid >> 6;
  const int li16 = lane & 15, q4 = lane >> 4;
  const int t0 = blockIdx.x * 32;
  const int e0 = blockIdx.y * 128;

  if (tid < 32) {
    int s = t0 + tid;
    float c0 = countf(PADL + s);
    float c1 = countf(PADL + ((s + 64) & (TLEN - 1)));
    float fA = 0.5f / (c0 + 1e-6f), fB = 0.5f / (c1 + 1e-6f);
    cfA[tid] = fA; cfB[tid] = fB;
    bscL[tid] = c0 * fA + c1 * fB;
  }
  if (tid < 128) msB[tid] = 0.0f;
  __syncthreads();

  for (int i = tid; i < 32 * 128; i += 512) {
    int rr = i >> 7, c2 = (i & 127) * 2;
    int s = t0 + rr;
    int s1 = (s + 64) & (TLEN - 1);
    float2 a0 = *(const float2*)&accg[(size_t)(PADL + s) * CDIM + c2];
    float2 a1 = *(const float2*)&accg[(size_t)TPAD * CDIM + (size_t)(PADL + s1) * CDIM + c2];
    float fA = cfA[rr], fB = cfB[rr];
    *(unsigned int*)&Ub[rr * 264 + c2] =
        pk2t(a0.x * fA + a1.x * fB, a0.y * fA + a1.y * fB);
  }
  __syncthreads();

  f32x4 acc[2];
  acc[0] = (f32x4){0.f, 0.f, 0.f, 0.f};
  acc[1] = (f32x4){0.f, 0.f, 0.f, 0.f};
  #pragma unroll
  for (int ks = 0; ks < 8; ++ks) {
    bf16x8 Bf = *(const bf16x8*)(Mtb + (size_t)(e0 + wv * 16 + li16) * 256 + ks * 32 + q4 * 8);
    #pragma unroll
    for (int it = 0; it < 2; ++it) {
      bf16x8 Af = *(bf16x8*)&Ub[(16 * it + li16) * 264 + ks * 32 + q4 * 8];
      acc[it] = __builtin_amdgcn_mfma_f32_16x16x32_bf16(Af, Bf, acc[it], 0, 0, 0);
    }
  }

  {
    int e = e0 + wv * 16 + li16;
    float vbe = vbv[e], pbe = pb[e];
    float part = 0.0f;
    #pragma unroll
    for (int it = 0; it < 2; ++it)
      #pragma unroll
      for (int r = 0; r < 4; ++r) {
        int rloc = 16 * it + 4 * q4 + r;
        float val = acc[it][r] + bscL[rloc] * vbe + pbe;
        z[(size_t)(t0 + rloc) * CDIM + e] = val;
        part += val;
      }
    atomicAdd(&msB[e - e0], part);
  }
  __syncthreads();
  if (tid < 128) atomicAdd(&msum[e0 + tid], msB[tid]);
}

// ---------------- fused SE gate + residual ----------------
__global__ void k_finalse(const float* __restrict__ x, const float* __restrict__ z,
                          const float* __restrict__ msum, const float* __restrict__ w1,
                          const float* __restrict__ w2, float* __restrict__ out) {
  __shared__ float red2[16][4];
  __shared__ float s1[16];
  __shared__ float gateS[256];
  int tid = threadIdx.x;
  int lane = tid & 63, wv = tid >> 6;
  float sm = msum[tid] * (1.0f / 1024.0f);
  #pragma unroll
  for (int r = 0; r < 16; ++r) {
    float v = sm * w1[(size_t)r * 256 + tid];
    #pragma unroll
    for (int m = 32; m >= 1; m >>= 1) v += __shfl_xor(v, m);
    if (lane == 0) red2[r][wv] = v;
  }
  __syncthreads();
  if (tid < 16) {
    float a = red2[tid][0] + red2[tid][1] + red2[tid][2] + red2[tid][3];
    s1[tid] = fmaxf(a, 0.0f);
  }
  __syncthreads();
  float gacc = 0.0f;
  #pragma unroll
  for (int i = 0; i < 16; ++i) gacc += s1[i] * w2[(size_t)tid * 16 + i];
  gateS[tid] = 1.0f / (1.0f + __expf(-gacc));
  __syncthreads();
  int i = blockIdx.x * 256 + tid;
  float4 xv = ((const float4*)x)[i];
  float4 zv = ((const float4*)z)[i];
  float4 gv = ((const float4*)gateS)[i & 63];
  float4 o;
  o.x = xv.x + zv.x * gv.x;
  o.y = xv.y + zv.y * gv.y;
  o.z = xv.z + zv.z * gv.z;
  o.w = xv.w + zv.w * gv.w;
  ((float4*)out)[i] = o;
}

extern "C" void kernel_launch(void* const* d_in, const int* in_sizes, int n_in,
                              void* d_out, int out_size, void* d_ws, size_t ws_size,
                              hipStream_t stream) {
  const float* x   = (const float*)d_in[0];
  const float* lng = (const float*)d_in[1];
  const float* lnb = (const float*)d_in[2];
  const float* ipw = (const float*)d_in[3];
  const float* ipb = (const float*)d_in[4];
  const float* ow  = (const float*)d_in[5];
  const float* ob  = (const float*)d_in[6];
  const float* pw  = (const float*)d_in[7];
  const float* pb  = (const float*)d_in[8];
  const float* w1  = (const float*)d_in[9];
  const float* w2  = (const float*)d_in[10];
  float* out = (float*)d_out;

  float* ws = (float*)d_ws;
  unsigned short* lnbf = (unsigned short*)ws;             // 131072 f
  unsigned short* Wb   = (unsigned short*)(ws + 131072);  // 98304 f
  unsigned short* Pbf  = (unsigned short*)(ws + 229376);  // 441600 f
  float* accg = ws + 229376 + 441600;                     // 588800 f
  unsigned short* Mtb = (unsigned short*)(accg + 588800); // 32768 f
  float* vbv  = accg + 588800 + 32768;                    // 256
  float* z    = vbv + 256;                                // 262144
  float* msum = z + 262144;                               // 256

  k_prep<<<dim3(640), dim3(256), 0, stream>>>(x, lng, lnb, lnbf, ipw, Wb,
                                              pw, ow, ob, Mtb, vbv, accg, Pbf, msum);
  k_proj<<<dim3(16, 6), dim3(512), 0, stream>>>(lnbf, Wb, Pbf);
  k_attn<<<dim3(32, NHEAD, 2), dim3(512), 0, stream>>>(Pbf, ipb, accg);
  k_comb<<<dim3(32, 2), dim3(512), 0, stream>>>(accg, Mtb, vbv, pb, z, msum);
  k_finalse<<<dim3(256), dim3(256), 0, stream>>>(x, z, msum, w1, w2, out);
}